// Round 3
// baseline (96.264 us; speedup 1.0000x reference)
//
#include <hip/hip_runtime.h>
#include <math.h>

#define BATCH 8
#define NTR   1024   // tracks per batch
// output: [BATCH*NTR, 32], float32

__global__ __launch_bounds__(256)
void knn_mlp_simple(const float* __restrict__ obs1,
                    const float* __restrict__ obs2,
                    const float* __restrict__ W,
                    const float* __restrict__ bias,
                    float* __restrict__ out)
{
    __shared__ float2 sh_pos[NTR];   // obs2[batch]
    __shared__ float2 sh_vel[NTR];   // obs2 - obs1

    const int tid   = threadIdx.x;
    const int batch = blockIdx.x >> 2;             // 4 blocks per batch
    const int i     = ((blockIdx.x & 3) << 8) + tid;   // row in [0, 1024)

    // ---- stage obs2 and vel into LDS (coalesced float2) ----
    const float2* __restrict__ p2 = (const float2*)(obs2 + (size_t)batch * NTR * 2);
    const float2* __restrict__ p1 = (const float2*)(obs1 + (size_t)batch * NTR * 2);
    for (int t = 0; t < 4; ++t) {
        const int idx = tid + (t << 8);
        const float2 o2 = p2[idx];
        const float2 o1 = p1[idx];
        sh_pos[idx] = o2;
        sh_vel[idx] = make_float2(o2.x - o1.x, o2.y - o1.y);
    }
    __syncthreads();

    const float2 my = sh_pos[i];

    // ---- serial scan: branchless sorted top-4 of (dist, j) ----
    float d0 = 3e38f, d1 = 3e38f, d2 = 3e38f, d3 = 3e38f;
    int   i0 = 0,     i1 = 0,     i2 = 0,     i3 = 0;

    for (int j = 0; j < NTR; ++j) {
        const float2 pj = sh_pos[j];            // wave-uniform broadcast read
        const float dx = pj.x - my.x;
        const float dy = pj.y - my.y;
        // unfused x*x + y*y then sqrt, matching the reference
        const float dd = __fadd_rn(__fmul_rn(dx, dx), __fmul_rn(dy, dy));
        float dist = sqrtf(dd);
        dist = (j == i) ? 3e38f : dist;         // skip diagonal

        // strict < keeps lower j on ties (j ascending) == lax.top_k tie-break
        const bool c3 = dist < d3;
        const bool c2 = dist < d2;
        const bool c1 = dist < d1;
        const bool c0 = dist < d0;
        d3 = c2 ? d2 : (c3 ? dist : d3);  i3 = c2 ? i2 : (c3 ? j : i3);
        d2 = c1 ? d1 : (c2 ? dist : d2);  i2 = c1 ? i1 : (c2 ? j : i2);
        d1 = c0 ? d0 : (c1 ? dist : d1);  i1 = c0 ? i0 : (c1 ? j : i1);
        d0 = c0 ? dist : d0;              i0 = c0 ? j  : i0;
    }

    // ---- per-row MLP: 4 neighbors x 8 embedding dims ----
    const float2 vi = sh_vel[i];
    const int nb[4] = { i0, i1, i2, i3 };
    float res[32];
#pragma unroll
    for (int k = 0; k < 4; ++k) {
        const int j = nb[k];
        const float2 pj = sh_pos[j];
        const float2 vj = sh_vel[j];
        const float f0 = pj.x - my.x;
        const float f1 = pj.y - my.y;
        const float f2 = vj.x - vi.x;
        const float f3 = vj.y - vi.y;
#pragma unroll
        for (int e = 0; e < 8; ++e) {
            const float4 w = ((const float4*)W)[e];
            float r = f0 * w.x + f1 * w.y + f2 * w.z + f3 * w.w + bias[e];
            res[k * 8 + e] = fmaxf(r, 0.0f);
        }
    }

    float4* op = (float4*)(out + ((size_t)(batch * NTR + i) << 5));
#pragma unroll
    for (int q = 0; q < 8; ++q)
        op[q] = make_float4(res[q * 4 + 0], res[q * 4 + 1],
                            res[q * 4 + 2], res[q * 4 + 3]);
}

extern "C" void kernel_launch(void* const* d_in, const int* in_sizes, int n_in,
                              void* d_out, int out_size, void* d_ws, size_t ws_size,
                              hipStream_t stream) {
    const float* obs1 = (const float*)d_in[0];
    const float* obs2 = (const float*)d_in[1];
    const float* W    = (const float*)d_in[2];
    const float* bias = (const float*)d_in[3];
    float* out = (float*)d_out;

    const int grid = BATCH * 4;   // 32 blocks x 256 threads = one thread per row
    knn_mlp_simple<<<grid, 256, 0, stream>>>(obs1, obs2, W, bias, out);
}

// Round 4
// 18.368 us; speedup vs baseline: 5.2409x; 5.2409x over previous
//
#include <hip/hip_runtime.h>
#include <math.h>

#define BATCH 8
#define NTR   1024     // tracks per batch
#define RPB   16       // rows per block
#define TPR   16       // threads per row
#define NSEG  (NTR / TPR)   // candidates per thread = 64
// output: [BATCH*NTR, 32], float32

// lexicographic (dist,idx) compare: true if (bd,bi) < (ad,ai)
__device__ __forceinline__ bool lex_lt(float bd, int bi, float ad, int ai) {
    return (bd < ad) || ((bd == ad) && (bi < ai));
}

__device__ __forceinline__ void lex_min(float& dd, int& di,
                                        float ad, int ai, float bd, int bi) {
    const bool sw = lex_lt(bd, bi, ad, ai);
    dd = sw ? bd : ad;
    di = sw ? bi : ai;
}

// compare-exchange: after call (ad,ai) <= (bd,bi)
__device__ __forceinline__ void lex_ce(float& ad, int& ai, float& bd, int& bi) {
    const bool sw = lex_lt(bd, bi, ad, ai);
    const float tlo = sw ? bd : ad;
    const float thi = sw ? ad : bd;
    const int   ulo = sw ? bi : ai;
    const int   uhi = sw ? ai : bi;
    ad = tlo; bd = thi; ai = ulo; bi = uhi;
}

__global__ __launch_bounds__(256)
void knn_mlp_par(const float* __restrict__ obs1,
                 const float* __restrict__ obs2,
                 const float* __restrict__ W,
                 const float* __restrict__ bias,
                 float* __restrict__ out)
{
    __shared__ float2 sh_pos[NTR];        // obs2[batch]
    __shared__ float2 sh_vel[NTR];        // obs2 - obs1
    __shared__ float  sh_d[RPB * TPR * 4];
    __shared__ int    sh_i[RPB * TPR * 4];

    const int tid = threadIdx.x;
    const int blocksPerBatch = NTR / RPB;                 // 64
    const int batch   = blockIdx.x / blocksPerBatch;
    const int rowbase = (blockIdx.x % blocksPerBatch) * RPB;

    // ---- stage obs2 and vel into LDS (coalesced float2) ----
    const float2* __restrict__ p2 = (const float2*)(obs2 + (size_t)batch * NTR * 2);
    const float2* __restrict__ p1 = (const float2*)(obs1 + (size_t)batch * NTR * 2);
#pragma unroll
    for (int t = 0; t < 4; ++t) {
        const int idx = tid + (t << 8);
        const float2 o2 = p2[idx];
        const float2 o1 = p1[idx];
        sh_pos[idx] = o2;
        sh_vel[idx] = make_float2(o2.x - o1.x, o2.y - o1.y);
    }
    __syncthreads();

    const int r = tid >> 4;        // row within block 0..15
    const int s = tid & 15;        // segment 0..15
    const int i = rowbase + r;     // this row's index in batch

    const float2 my = sh_pos[i];

    // ---- strided scan: branchless sorted top-4 of (dist, j) ----
    float d0 = 3e38f, d1 = 3e38f, d2 = 3e38f, d3 = 3e38f;
    int   i0 = 0x7ffffffe, i1 = 0x7ffffffe, i2 = 0x7ffffffe, i3 = 0x7ffffffe;

#pragma unroll 8
    for (int c = 0; c < NSEG; ++c) {
        const int j = s + (c << 4);          // stride TPR: conflict-free banks
        const float2 pj = sh_pos[j];
        const float dx = pj.x - my.x;
        const float dy = pj.y - my.y;
        // unfused x*x + y*y then sqrt, matching the reference
        const float dd = __fadd_rn(__fmul_rn(dx, dx), __fmul_rn(dy, dy));
        float dist = sqrtf(dd);
        dist = (j == i) ? 3e38f : dist;      // mask diagonal

        // strict < keeps lower j on ties (j ascending within thread)
        const bool c3 = dist < d3;
        const bool c2 = dist < d2;
        const bool c1 = dist < d1;
        const bool c0 = dist < d0;
        d3 = c2 ? d2 : (c3 ? dist : d3);  i3 = c2 ? i2 : (c3 ? j : i3);
        d2 = c1 ? d1 : (c2 ? dist : d2);  i2 = c1 ? i1 : (c2 ? j : i2);
        d1 = c0 ? d0 : (c1 ? dist : d1);  i1 = c0 ? i0 : (c1 ? j : i1);
        d0 = c0 ? dist : d0;              i0 = c0 ? j  : i0;
    }

    // ---- write per-thread sorted-4 to LDS ----
    {
        const int a = tid << 2;     // (r*TPR + s)*4 == tid*4
        sh_d[a+0] = d0; sh_d[a+1] = d1; sh_d[a+2] = d2; sh_d[a+3] = d3;
        sh_i[a+0] = i0; sh_i[a+1] = i1; sh_i[a+2] = i2; sh_i[a+3] = i3;
    }

    // ---- 4-level LDS tree merge: 16 sorted-4 lists -> 1 per row ----
    for (int half = TPR >> 1; half >= 1; half >>= 1) {
        __syncthreads();
        if (s < half) {
            const int a = tid << 2;
            const int b = ((r * TPR) + s + half) << 2;
            float a0 = sh_d[a+0], a1 = sh_d[a+1], a2 = sh_d[a+2], a3 = sh_d[a+3];
            int   x0 = sh_i[a+0], x1 = sh_i[a+1], x2 = sh_i[a+2], x3 = sh_i[a+3];
            float b0 = sh_d[b+0], b1 = sh_d[b+1], b2 = sh_d[b+2], b3 = sh_d[b+3];
            int   y0 = sh_i[b+0], y1 = sh_i[b+1], y2 = sh_i[b+2], y3 = sh_i[b+3];

            float t0, t1, t2, t3; int u0, u1, u2, u3;
            lex_min(t0, u0, a0, x0, b3, y3);
            lex_min(t1, u1, a1, x1, b2, y2);
            lex_min(t2, u2, a2, x2, b1, y1);
            lex_min(t3, u3, a3, x3, b0, y0);
            lex_ce(t0, u0, t2, u2);
            lex_ce(t1, u1, t3, u3);
            lex_ce(t0, u0, t1, u1);
            lex_ce(t2, u2, t3, u3);

            sh_d[a+0] = t0; sh_d[a+1] = t1; sh_d[a+2] = t2; sh_d[a+3] = t3;
            sh_i[a+0] = u0; sh_i[a+1] = u1; sh_i[a+2] = u2; sh_i[a+3] = u3;
        }
    }
    __syncthreads();

    // ---- epilogue: 512 outputs per block, 2 per thread, coalesced ----
#pragma unroll
    for (int q = 0; q < 2; ++q) {
        const int o  = tid + (q << 8);       // 0..511
        const int rr = o >> 5;               // row within block
        const int kk = (o >> 3) & 3;         // neighbor rank
        const int e  = o & 7;                // embedding dim

        int j = sh_i[((rr * TPR) << 2) + kk];
        j = (j < 0) ? 0 : ((j > NTR - 1) ? NTR - 1 : j);   // defensive clamp

        const float2 pj  = sh_pos[j];
        const float2 vj  = sh_vel[j];
        const float2 myr = sh_pos[rowbase + rr];
        const float2 vir = sh_vel[rowbase + rr];
        const float f0 = pj.x - myr.x;
        const float f1 = pj.y - myr.y;
        const float f2 = vj.x - vir.x;
        const float f3 = vj.y - vir.y;

        const float4 w = ((const float4*)W)[e];
        float res = f0 * w.x + f1 * w.y + f2 * w.z + f3 * w.w + bias[e];
        res = fmaxf(res, 0.0f);

        out[(((size_t)(batch * NTR + rowbase)) << 5) + o] = res;
    }
}

extern "C" void kernel_launch(void* const* d_in, const int* in_sizes, int n_in,
                              void* d_out, int out_size, void* d_ws, size_t ws_size,
                              hipStream_t stream) {
    const float* obs1 = (const float*)d_in[0];
    const float* obs2 = (const float*)d_in[1];
    const float* W    = (const float*)d_in[2];
    const float* bias = (const float*)d_in[3];
    float* out = (float*)d_out;

    const int grid = BATCH * (NTR / RPB);   // 512 blocks
    knn_mlp_par<<<grid, 256, 0, stream>>>(obs1, obs2, W, bias, out);
}

// Round 5
// 15.673 us; speedup vs baseline: 6.1419x; 1.1719x over previous
//
#include <hip/hip_runtime.h>
#include <math.h>

#define BATCH 8
#define NTR   1024     // tracks per batch
#define RPB   8        // rows per block
#define TPR   32       // threads per row
#define NSEG  (NTR / TPR)   // candidates per thread = 32
// output: [BATCH*NTR, 32], float32

// lexicographic (key,idx) compare: true if (bd,bi) < (ad,ai)
__device__ __forceinline__ bool lex_lt(float bd, int bi, float ad, int ai) {
    return (bd < ad) || ((bd == ad) && (bi < ai));
}

__device__ __forceinline__ void lex_min(float& dd, int& di,
                                        float ad, int ai, float bd, int bi) {
    const bool sw = lex_lt(bd, bi, ad, ai);
    dd = sw ? bd : ad;
    di = sw ? bi : ai;
}

// compare-exchange: after call (ad,ai) <= (bd,bi)
__device__ __forceinline__ void lex_ce(float& ad, int& ai, float& bd, int& bi) {
    const bool sw = lex_lt(bd, bi, ad, ai);
    const float tlo = sw ? bd : ad;
    const float thi = sw ? ad : bd;
    const int   ulo = sw ? bi : ai;
    const int   uhi = sw ? ai : bi;
    ad = tlo; bd = thi; ai = ulo; bi = uhi;
}

__global__ __launch_bounds__(256)
void knn_mlp_par(const float* __restrict__ obs1,
                 const float* __restrict__ obs2,
                 const float* __restrict__ W,
                 const float* __restrict__ bias,
                 float* __restrict__ out)
{
    __shared__ __align__(16) float2 sh_pos[NTR];   // obs2[batch]
    __shared__ __align__(16) float2 sh_vel[NTR];   // obs2 - obs1
    __shared__ float  sh_d[RPB * TPR * 4];
    __shared__ int    sh_i[RPB * TPR * 4];

    const int tid = threadIdx.x;
    const int blocksPerBatch = NTR / RPB;                 // 128
    const int batch   = blockIdx.x / blocksPerBatch;
    const int rowbase = (blockIdx.x % blocksPerBatch) * RPB;

    // ---- stage obs2 and vel into LDS (float4 = 2 tracks per op) ----
    const float4* __restrict__ p2 = (const float4*)(obs2 + (size_t)batch * NTR * 2);
    const float4* __restrict__ p1 = (const float4*)(obs1 + (size_t)batch * NTR * 2);
    float4* sp4 = (float4*)sh_pos;
    float4* sv4 = (float4*)sh_vel;
#pragma unroll
    for (int t = 0; t < 2; ++t) {
        const int idx = tid + (t << 8);        // 0..511
        const float4 o2 = p2[idx];
        const float4 o1 = p1[idx];
        sp4[idx] = o2;
        sv4[idx] = make_float4(o2.x - o1.x, o2.y - o1.y,
                               o2.z - o1.z, o2.w - o1.w);
    }
    __syncthreads();

    const int r = tid >> 5;        // row within block 0..7
    const int s = tid & 31;        // segment 0..31
    const int i = rowbase + r;     // this row's index in batch

    const float2 my = sh_pos[i];

    // ---- strided scan: branchless sorted top-4 of (dd, j) ----
    // sqrt is monotone, so ranking by squared distance == ranking by distance
    float d0 = 3e38f, d1 = 3e38f, d2 = 3e38f, d3 = 3e38f;
    int   i0 = 0x7ffffffe, i1 = 0x7ffffffe, i2 = 0x7ffffffe, i3 = 0x7ffffffe;

#pragma unroll 8
    for (int c = 0; c < NSEG; ++c) {
        const int j = s + (c << 5);          // stride TPR
        const float2 pj = sh_pos[j];
        const float dx = pj.x - my.x;
        const float dy = pj.y - my.y;
        // unfused x*x + y*y, matching the reference's norm argument
        float dd = __fadd_rn(__fmul_rn(dx, dx), __fmul_rn(dy, dy));
        dd = (j == i) ? 3e38f : dd;          // mask diagonal

        // strict < keeps lower j on ties (j ascending within thread)
        const bool c3 = dd < d3;
        const bool c2 = dd < d2;
        const bool c1 = dd < d1;
        const bool c0 = dd < d0;
        d3 = c2 ? d2 : (c3 ? dd : d3);  i3 = c2 ? i2 : (c3 ? j : i3);
        d2 = c1 ? d1 : (c2 ? dd : d2);  i2 = c1 ? i1 : (c2 ? j : i2);
        d1 = c0 ? d0 : (c1 ? dd : d1);  i1 = c0 ? i0 : (c1 ? j : i1);
        d0 = c0 ? dd : d0;              i0 = c0 ? j  : i0;
    }

    // ---- write per-thread sorted-4 to LDS ----
    {
        const int a = tid << 2;
        sh_d[a+0] = d0; sh_d[a+1] = d1; sh_d[a+2] = d2; sh_d[a+3] = d3;
        sh_i[a+0] = i0; sh_i[a+1] = i1; sh_i[a+2] = i2; sh_i[a+3] = i3;
    }

    // ---- 5-level LDS tree merge: 32 sorted-4 lists -> 1 per row ----
    for (int half = TPR >> 1; half >= 1; half >>= 1) {
        __syncthreads();
        if (s < half) {
            const int a = tid << 2;
            const int b = ((r * TPR) + s + half) << 2;
            float a0 = sh_d[a+0], a1 = sh_d[a+1], a2 = sh_d[a+2], a3 = sh_d[a+3];
            int   x0 = sh_i[a+0], x1 = sh_i[a+1], x2 = sh_i[a+2], x3 = sh_i[a+3];
            float b0 = sh_d[b+0], b1 = sh_d[b+1], b2 = sh_d[b+2], b3 = sh_d[b+3];
            int   y0 = sh_i[b+0], y1 = sh_i[b+1], y2 = sh_i[b+2], y3 = sh_i[b+3];

            float t0, t1, t2, t3; int u0, u1, u2, u3;
            lex_min(t0, u0, a0, x0, b3, y3);
            lex_min(t1, u1, a1, x1, b2, y2);
            lex_min(t2, u2, a2, x2, b1, y1);
            lex_min(t3, u3, a3, x3, b0, y0);
            lex_ce(t0, u0, t2, u2);
            lex_ce(t1, u1, t3, u3);
            lex_ce(t0, u0, t1, u1);
            lex_ce(t2, u2, t3, u3);

            sh_d[a+0] = t0; sh_d[a+1] = t1; sh_d[a+2] = t2; sh_d[a+3] = t3;
            sh_i[a+0] = u0; sh_i[a+1] = u1; sh_i[a+2] = u2; sh_i[a+3] = u3;
        }
    }
    __syncthreads();

    // ---- epilogue: 256 outputs per block, 1 per thread, coalesced ----
    {
        const int o  = tid;                  // 0..255
        const int rr = o >> 5;               // row within block
        const int kk = (o >> 3) & 3;         // neighbor rank
        const int e  = o & 7;                // embedding dim

        int j = sh_i[((rr * TPR) << 2) + kk];
        j = (j < 0) ? 0 : ((j > NTR - 1) ? NTR - 1 : j);   // defensive clamp

        const float2 pj  = sh_pos[j];
        const float2 vj  = sh_vel[j];
        const float2 myr = sh_pos[rowbase + rr];
        const float2 vir = sh_vel[rowbase + rr];
        const float f0 = pj.x - myr.x;
        const float f1 = pj.y - myr.y;
        const float f2 = vj.x - vir.x;
        const float f3 = vj.y - vir.y;

        const float4 w = ((const float4*)W)[e];
        float res = f0 * w.x + f1 * w.y + f2 * w.z + f3 * w.w + bias[e];
        res = fmaxf(res, 0.0f);

        out[(((size_t)(batch * NTR + rowbase)) << 5) + o] = res;
    }
}

extern "C" void kernel_launch(void* const* d_in, const int* in_sizes, int n_in,
                              void* d_out, int out_size, void* d_ws, size_t ws_size,
                              hipStream_t stream) {
    const float* obs1 = (const float*)d_in[0];
    const float* obs2 = (const float*)d_in[1];
    const float* W    = (const float*)d_in[2];
    const float* bias = (const float*)d_in[3];
    float* out = (float*)d_out;

    const int grid = BATCH * (NTR / RPB);   // 1024 blocks = 4 per CU
    knn_mlp_par<<<grid, 256, 0, stream>>>(obs1, obs2, W, bias, out);
}